// Round 4
// baseline (558.907 us; speedup 1.0000x reference)
//
#include <hip/hip_runtime.h>

#define NTAGS 48
#define NB    512
#define SLEN  2048

// ---------- cross-lane helpers (wave64, DPP) ----------

__device__ __forceinline__ float rl_f(float v, int l) {
  return __builtin_bit_cast(float, __builtin_amdgcn_readlane(__builtin_bit_cast(int, v), l));
}

template <int CTRL, bool BC>
__device__ __forceinline__ float dpp_mv(float oldv, float v) {
  return __builtin_bit_cast(float, __builtin_amdgcn_update_dpp(
      __builtin_bit_cast(int, oldv), __builtin_bit_cast(int, v), CTRL, 0xF, 0xF, BC));
}

__device__ __forceinline__ float wred_max(float v) {
  v = fmaxf(v, dpp_mv<0x128, false>(v, v));
  v = fmaxf(v, dpp_mv<0x124, false>(v, v));
  v = fmaxf(v, dpp_mv<0x122, false>(v, v));
  v = fmaxf(v, dpp_mv<0x121, false>(v, v));
  v = fmaxf(v, dpp_mv<0x142, false>(v, v));
  v = fmaxf(v, dpp_mv<0x143, false>(v, v));
  return rl_f(v, 63);
}

__device__ __forceinline__ float wred_sum(float v) {
  v += dpp_mv<0x128, true>(0.0f, v);
  v += dpp_mv<0x124, true>(0.0f, v);
  v += dpp_mv<0x122, true>(0.0f, v);
  v += dpp_mv<0x121, true>(0.0f, v);
  v += dpp_mv<0x142, true>(0.0f, v);
  v += dpp_mv<0x143, true>(0.0f, v);
  return rl_f(v, 63);
}

// Independent row_ror:K — full-rate VALU, dst[c] = src[row, (c+K)&15].
// R3's bug: chained ror1 (15-deep dependent DPP chain, ~8cy each = ~760cy/step).
// Fix: all 15 rotations read the ORIGINAL source -> issue back-to-back.
#define ROR(K, V) dpp_mv<0x120 + (K), false>((V), (V))

// One 16-wide phase: AE/AO are the even/odd-k accumulators (same pairing and
// order as r3 -> identical numerics).
#define PH16(SRC, B, AE, AO)                          \
  AE = fmaf((SRC),          Evp[(B) + 0],  AE);       \
  AO = fmaf(ROR(1, (SRC)),  Evp[(B) + 1],  AO);       \
  AE = fmaf(ROR(2, (SRC)),  Evp[(B) + 2],  AE);       \
  AO = fmaf(ROR(3, (SRC)),  Evp[(B) + 3],  AO);       \
  AE = fmaf(ROR(4, (SRC)),  Evp[(B) + 4],  AE);       \
  AO = fmaf(ROR(5, (SRC)),  Evp[(B) + 5],  AO);       \
  AE = fmaf(ROR(6, (SRC)),  Evp[(B) + 6],  AE);       \
  AO = fmaf(ROR(7, (SRC)),  Evp[(B) + 7],  AO);       \
  AE = fmaf(ROR(8, (SRC)),  Evp[(B) + 8],  AE);       \
  AO = fmaf(ROR(9, (SRC)),  Evp[(B) + 9],  AO);       \
  AE = fmaf(ROR(10, (SRC)), Evp[(B) + 10], AE);       \
  AO = fmaf(ROR(11, (SRC)), Evp[(B) + 11], AO);       \
  AE = fmaf(ROR(12, (SRC)), Evp[(B) + 12], AE);       \
  AO = fmaf(ROR(13, (SRC)), Evp[(B) + 13], AO);       \
  AE = fmaf(ROR(14, (SRC)), Evp[(B) + 14], AE);       \
  AO = fmaf(ROR(15, (SRC)), Evp[(B) + 15], AO);

// 48-wide matvec: 45 independent DPP rors + 48 fma + 3 bpermute (^16/^32/^48,
// latency hidden under phase 0). Source-row selection per 16-lane row is
// identical to r3 (validated): phase0 own row; phase1 (r==2)?C:B; phase2
// (r==0)?C:D. Evp pre-permuted per lane: Evp[ph*16+k] weights arrival
// (srcrow, (c+k)&15).
__device__ __forceinline__ float rotdot48(float p, const float* Evp,
                                          int a16, int a32, int a48,
                                          bool isr2, bool isr0) {
  const int pi = __builtin_bit_cast(int, p);
  const float Bf = __builtin_bit_cast(float, __builtin_amdgcn_ds_bpermute(a16, pi));
  const float Cf = __builtin_bit_cast(float, __builtin_amdgcn_ds_bpermute(a32, pi));
  const float Df = __builtin_bit_cast(float, __builtin_amdgcn_ds_bpermute(a48, pi));
  float a0 = 0.f, a1 = 0.f, a2 = 0.f, a3 = 0.f, a4 = 0.f, a5 = 0.f;
  PH16(p, 0, a0, a1);                 // own row while bpermutes are in flight
  float t = isr2 ? Cf : Bf;
  PH16(t, 16, a2, a3);
  float u = isr0 ? Cf : Df;
  PH16(u, 32, a4, a5);
  return ((a0 + a1) + (a2 + a3)) + (a4 + a5);
}

// exact pow2 renorm: p *= 2^-e, cl += e*ln2
__device__ __forceinline__ void renorm(float& p, float& cl) {
  float mx = wred_max(p);
  int e = ((__builtin_bit_cast(int, mx) >> 23) & 255) - 127;
  float r = __builtin_bit_cast(float, (127 - e) << 23);
  p *= r;
  cl += (float)e * 0.6931471805599453f;
}

// ---------- fused kernel ----------
// blocks [0,1024): scan. even = forward half (alpha_1024), odd = backward half (beta_1024).
// blocks [1024,1536): gold-path score + mask count, one wave per batch.

extern "C" __global__ __launch_bounds__(64, 1)
void crf_main(const float* __restrict__ emis,
              const float* __restrict__ trans,
              const float* __restrict__ startt,
              const float* __restrict__ endt,
              const int*   __restrict__ tags,
              const float* __restrict__ mask,
              float* __restrict__ wa, float* __restrict__ wb,
              float* __restrict__ wsc, int* __restrict__ wcnt) {
  __shared__ float st[NTAGS * NTAGS];
  const int lane = threadIdx.x;
  const int bid  = blockIdx.x;

  if (bid >= 2 * NB) {
    // ----- score path -----
    const int b = bid - 2 * NB;
    for (int k = lane; k < NTAGS * NTAGS; k += 64) st[k] = trans[k];
    __syncthreads();
    const int* tb = tags + (size_t)b * SLEN;
    float ssum = 0.0f, csum = 0.0f;
    for (int it = 0; it < SLEN / 64; ++it) {
      const int t   = it * 64 + lane;
      int   cur = tb[t];
      float mv  = mask[(size_t)b * SLEN + t];
      float ev  = emis[((size_t)b * SLEN + t) * NTAGS + cur];
      float s;
      if (t == 0) {
        s = startt[cur] + ev;  // unmasked per reference
      } else {
        int prev = tb[t - 1];
        s = (mv != 0.0f) ? (st[prev * NTAGS + cur] + ev) : 0.0f;
      }
      ssum += s;
      csum += (mv != 0.0f) ? 1.0f : 0.0f;
    }
    ssum = wred_sum(ssum);
    csum = wred_sum(csum);
    if (lane == 0) { wsc[b] = ssum; wcnt[b] = (int)(csum + 0.5f); }
    return;
  }

  // ----- scan path -----
  const int  b   = bid >> 1;
  const bool fwd = (bid & 1) == 0;
  const int  r   = lane >> 4, c = lane & 15;
  const bool isr2 = (r == 2), isr0 = (r == 0);
  const int  a16 = (lane ^ 16) << 2;
  const int  a32 = (lane ^ 32) << 2;
  const int  a48 = (lane ^ 48) << 2;
  const int  jc  = lane < NTAGS ? lane : (NTAGS - 1);  // pad lanes mirror lane 47

  const float* eb = emis + (size_t)b * SLEN * NTAGS;
  const float* mb = mask + (size_t)b * SLEN;

  // per-lane pre-permuted exp(trans) table matching the rotation schedule
  float Evp[48];
  {
    const int d0 = r;
    const int d1 = isr2 ? 0 : (r ^ 1);
    const int d2 = isr0 ? 2 : (r ^ 3);
    const int drs[3] = {d0, d1, d2};
#pragma unroll
    for (int ph = 0; ph < 3; ++ph) {
#pragma unroll
      for (int k = 0; k < 16; ++k) {
        int i = 16 * drs[ph] + ((c + k) & 15);
        if (i > 47) i = 47;  // pad rows only; their products multiply pad data
        Evp[ph * 16 + k] = __expf(fwd ? trans[i * NTAGS + jc]
                                      : trans[jc * NTAGS + i]);
      }
    }
  }

  float ebuf[8];  // 8-deep emission prefetch ring, slot = t & 7
  float p, cl, een;

  if (fwd) {
    float mnext = mb[1 + (lane & 7)];  // masks for group 0 (bits 0..7 of ballot)
    float a0 = startt[jc] + eb[jc];
    if (lane >= NTAGS) a0 = -1e30f;
    float m0 = wred_max(a0);
    p  = __expf(a0 - m0);   // pad lanes: exp(-1e30-m0) = 0 -> stay harmless
    cl = m0;
#pragma unroll
    for (int k = 1; k <= 8; ++k) ebuf[k & 7] = eb[(size_t)k * NTAGS + jc];
    een = __expf(ebuf[1]);  // exp(emit_1)

    for (int g = 0; g < 128; ++g) {
      const int t0 = 1 + 8 * g;
      const uint32_t m8 = (uint32_t)__ballot(mnext != 0.0f) & 0xffu;
      mnext = mb[(size_t)(t0 + 8) + (lane & 7)];   // prefetch next group's masks
      if (m8 == 0xffu) {
        // fast path: all masked-in, no select on the chain
#pragma unroll
        for (int u = 0; u < 8; ++u) {
          const int t = t0 + u;
          float ee = een;                       // exp(emit_t), off-chain
          een = __expf(ebuf[(t + 1) & 7]);
          float acc = rotdot48(p, Evp, a16, a32, a48, isr2, isr0);
          p = acc * ee;
          ebuf[t & 7] = eb[(size_t)(t + 8) * NTAGS + jc];  // prefetch t+8
          if (u == 7) renorm(p, cl);
        }
      } else {
#pragma unroll
        for (int u = 0; u < 8; ++u) {
          const int t = t0 + u;
          float ee = een;
          een = __expf(ebuf[(t + 1) & 7]);
          float acc = rotdot48(p, Evp, a16, a32, a48, isr2, isr0);
          float pn  = acc * ee;
          p = ((m8 >> u) & 1u) ? pn : p;
          ebuf[t & 7] = eb[(size_t)(t + 8) * NTAGS + jc];
          if (u == 7) renorm(p, cl);
        }
      }
    }
    if (lane < NTAGS) wa[b * NTAGS + lane] = __logf(p) + cl;
  } else {
    float mnext = mb[2040 - (lane & 7)];  // masks for group 0 of main loop
    float b0 = endt[jc];
    if (lane >= NTAGS) b0 = -1e30f;
    float m0 = wred_max(b0);
    p  = __expf(b0 - m0);
    cl = m0;
#pragma unroll
    for (int k = 0; k < 8; ++k) ebuf[(2047 - k) & 7] = eb[(size_t)(2047 - k) * NTAGS + jc];
    float q = p * __expf(ebuf[7]);  // q_2047 = beta_2047 * exp(emit_2047)
    een = __expf(ebuf[6]);          // exp(emit_2046)

    // peel t = 2047..2041 to align groups of 8 (mask via per-step loads; off hot path)
#pragma unroll
    for (int pt = 0; pt < 7; ++pt) {
      const int t = 2047 - pt;
      float ee = een;                       // exp(emit_{t-1})
      een = __expf(ebuf[(t + 6) & 7]);      // emit_{t-2}
      float acc = rotdot48(q, Evp, a16, a32, a48, isr2, isr0);  // beta_{t-1}
      float mv  = mb[t];
      p = (mv != 0.0f) ? acc : p;
      ebuf[t & 7] = eb[(size_t)(t - 8) * NTAGS + jc];
      if (pt == 6) renorm(p, cl);
      q = p * ee;
    }
    for (int g = 0; g < 127; ++g) {
      const int t0 = 2040 - 8 * g;
      const uint32_t m8 = (uint32_t)__ballot(mnext != 0.0f) & 0xffu;  // bit u <-> t0-u
      mnext = mb[(size_t)(t0 - 8) - (lane & 7)];
      if (m8 == 0xffu) {
#pragma unroll
        for (int u = 0; u < 8; ++u) {
          const int t = t0 - u;               // down to 1025
          float ee = een;
          een = __expf(ebuf[(t + 6) & 7]);
          float acc = rotdot48(q, Evp, a16, a32, a48, isr2, isr0);
          p = acc;
          ebuf[t & 7] = eb[(size_t)(t - 8) * NTAGS + jc];
          if (u == 7) renorm(p, cl);
          q = p * ee;
        }
      } else {
#pragma unroll
        for (int u = 0; u < 8; ++u) {
          const int t = t0 - u;
          float ee = een;
          een = __expf(ebuf[(t + 6) & 7]);
          float acc = rotdot48(q, Evp, a16, a32, a48, isr2, isr0);
          p = ((m8 >> u) & 1u) ? acc : p;
          ebuf[t & 7] = eb[(size_t)(t - 8) * NTAGS + jc];
          if (u == 7) renorm(p, cl);
          q = p * ee;
        }
      }
    }
    if (lane < NTAGS) wb[b * NTAGS + lane] = __logf(p) + cl;
  }
}

// ---------- combine: one block, one thread per batch; no atomics ----------

extern "C" __global__ __launch_bounds__(512)
void crf_combine(const float* __restrict__ wa, const float* __restrict__ wb,
                 const float* __restrict__ wsc, const int* __restrict__ wcnt,
                 const int* __restrict__ tags, const float* __restrict__ endt,
                 float* __restrict__ out) {
  __shared__ float red[8];
  const int b = threadIdx.x;  // 512 threads = 512 batches
  float vv[NTAGS];
  float m = -1e30f;
#pragma unroll
  for (int j = 0; j < NTAGS; ++j) {
    vv[j] = wa[b * NTAGS + j] + wb[b * NTAGS + j];
    m = fmaxf(m, vv[j]);
  }
  float s = 0.0f;
#pragma unroll
  for (int j = 0; j < NTAGS; ++j) s += __expf(vv[j] - m);
  float part = m + __logf(s);
  const int   last  = wcnt[b] - 1;
  const float score = wsc[b] + endt[tags[(size_t)b * SLEN + last]];
  float val = (part - score) * (1.0f / (float)NB);
  float wsum = wred_sum(val);
  if ((b & 63) == 0) red[b >> 6] = wsum;
  __syncthreads();
  if (b == 0) {
    float t = 0.0f;
#pragma unroll
    for (int w = 0; w < 8; ++w) t += red[w];
    *out = t;
  }
}

// ---------- launch ----------

extern "C" void kernel_launch(void* const* d_in, const int* in_sizes, int n_in,
                              void* d_out, int out_size, void* d_ws, size_t ws_size,
                              hipStream_t stream) {
  const float* emis  = (const float*)d_in[0];
  const float* trans = (const float*)d_in[1];
  const float* stt   = (const float*)d_in[2];
  const float* ent   = (const float*)d_in[3];
  const int*   tags  = (const int*)d_in[4];
  const float* mask  = (const float*)d_in[5];

  float* wa   = (float*)d_ws;            // [NB][NTAGS]
  float* wb   = wa + NB * NTAGS;         // [NB][NTAGS]
  float* wsc  = wb + NB * NTAGS;         // [NB]
  int*   wcnt = (int*)(wsc + NB);        // [NB]

  crf_main<<<2 * NB + NB, 64, 0, stream>>>(emis, trans, stt, ent, tags, mask,
                                           wa, wb, wsc, wcnt);
  crf_combine<<<1, 512, 0, stream>>>(wa, wb, wsc, wcnt, tags, ent, (float*)d_out);
}

// Round 5
// 412.893 us; speedup vs baseline: 1.3536x; 1.3536x over previous
//
#include <hip/hip_runtime.h>

#define NTAGS 48
#define NB    512
#define SLEN  2048

typedef float f32x2 __attribute__((ext_vector_type(2)));

// ---------- cross-lane helpers (wave64, DPP) ----------

__device__ __forceinline__ float rl_f(float v, int l) {
  return __builtin_bit_cast(float, __builtin_amdgcn_readlane(__builtin_bit_cast(int, v), l));
}

template <int CTRL, bool BC>
__device__ __forceinline__ float dpp_mv(float oldv, float v) {
  return __builtin_bit_cast(float, __builtin_amdgcn_update_dpp(
      __builtin_bit_cast(int, oldv), __builtin_bit_cast(int, v), CTRL, 0xF, 0xF, BC));
}

__device__ __forceinline__ float wred_max(float v) {
  v = fmaxf(v, dpp_mv<0x128, false>(v, v));
  v = fmaxf(v, dpp_mv<0x124, false>(v, v));
  v = fmaxf(v, dpp_mv<0x122, false>(v, v));
  v = fmaxf(v, dpp_mv<0x121, false>(v, v));
  v = fmaxf(v, dpp_mv<0x142, false>(v, v));
  v = fmaxf(v, dpp_mv<0x143, false>(v, v));
  return rl_f(v, 63);
}

__device__ __forceinline__ float wred_sum(float v) {
  v += dpp_mv<0x128, true>(0.0f, v);
  v += dpp_mv<0x124, true>(0.0f, v);
  v += dpp_mv<0x122, true>(0.0f, v);
  v += dpp_mv<0x121, true>(0.0f, v);
  v += dpp_mv<0x142, true>(0.0f, v);
  v += dpp_mv<0x143, true>(0.0f, v);
  return rl_f(v, 63);
}

// broadcast-dot: y = sum_{i<48} p[i] * Ev[i].
// Same instructions as r2 (48 v_readlane + 24 v_pk_fma, identical pairing and
// accumulation order -> bitwise-identical result), but software-pipelined in
// ONE asm block with THREE rotating SGPR banks (A=s80-83, B=s84-87, C=s88-91):
// readlane group g+1 issues between group g's readlanes and group g's FMAs,
// so every v_pk_fma reads SGPRs written >=5 instructions earlier (no
// SGPR-write->VALU-read hazard stalls). r2 reused one 4-SGPR bank with a
// 1-3 instruction write->read gap, paying ~2-3 stall cycles per readlane.
#define RL4(L0, L1, L2, L3, SA, SB, SC, SD)      \
  "v_readlane_b32 " SA ", %2, " #L0 "\n\t"       \
  "v_readlane_b32 " SB ", %2, " #L1 "\n\t"       \
  "v_readlane_b32 " SC ", %2, " #L2 "\n\t"       \
  "v_readlane_b32 " SD ", %2, " #L3 "\n\t"

#define FMA2(EA, EB, PA, PB)                     \
  "v_pk_fma_f32 %0, " PA ", " EA ", %0\n\t"      \
  "v_pk_fma_f32 %1, " PB ", " EB ", %1\n\t"

__device__ __forceinline__ float pipedot48(float pval, const f32x2* Ev2) {
  const int pv = __builtin_bit_cast(int, pval);
  f32x2 a01 = {0.0f, 0.0f};
  f32x2 a23 = {0.0f, 0.0f};
  asm(
    RL4(0, 1, 2, 3,     "s80", "s81", "s82", "s83")
    RL4(4, 5, 6, 7,     "s84", "s85", "s86", "s87")
    FMA2("%3",  "%4",   "s[80:81]", "s[82:83]")   // g0
    RL4(8, 9, 10, 11,   "s88", "s89", "s90", "s91")
    FMA2("%5",  "%6",   "s[84:85]", "s[86:87]")   // g1
    RL4(12, 13, 14, 15, "s80", "s81", "s82", "s83")
    FMA2("%7",  "%8",   "s[88:89]", "s[90:91]")   // g2
    RL4(16, 17, 18, 19, "s84", "s85", "s86", "s87")
    FMA2("%9",  "%10",  "s[80:81]", "s[82:83]")   // g3
    RL4(20, 21, 22, 23, "s88", "s89", "s90", "s91")
    FMA2("%11", "%12",  "s[84:85]", "s[86:87]")   // g4
    RL4(24, 25, 26, 27, "s80", "s81", "s82", "s83")
    FMA2("%13", "%14",  "s[88:89]", "s[90:91]")   // g5
    RL4(28, 29, 30, 31, "s84", "s85", "s86", "s87")
    FMA2("%15", "%16",  "s[80:81]", "s[82:83]")   // g6
    RL4(32, 33, 34, 35, "s88", "s89", "s90", "s91")
    FMA2("%17", "%18",  "s[84:85]", "s[86:87]")   // g7
    RL4(36, 37, 38, 39, "s80", "s81", "s82", "s83")
    FMA2("%19", "%20",  "s[88:89]", "s[90:91]")   // g8
    RL4(40, 41, 42, 43, "s84", "s85", "s86", "s87")
    FMA2("%21", "%22",  "s[80:81]", "s[82:83]")   // g9
    RL4(44, 45, 46, 47, "s88", "s89", "s90", "s91")
    FMA2("%23", "%24",  "s[84:85]", "s[86:87]")   // g10
    FMA2("%25", "%26",  "s[88:89]", "s[90:91]")   // g11
    : "+v"(a01), "+v"(a23)
    : "v"(pv),
      "v"(Ev2[0]),  "v"(Ev2[1]),  "v"(Ev2[2]),  "v"(Ev2[3]),
      "v"(Ev2[4]),  "v"(Ev2[5]),  "v"(Ev2[6]),  "v"(Ev2[7]),
      "v"(Ev2[8]),  "v"(Ev2[9]),  "v"(Ev2[10]), "v"(Ev2[11]),
      "v"(Ev2[12]), "v"(Ev2[13]), "v"(Ev2[14]), "v"(Ev2[15]),
      "v"(Ev2[16]), "v"(Ev2[17]), "v"(Ev2[18]), "v"(Ev2[19]),
      "v"(Ev2[20]), "v"(Ev2[21]), "v"(Ev2[22]), "v"(Ev2[23])
    : "s80", "s81", "s82", "s83", "s84", "s85",
      "s86", "s87", "s88", "s89", "s90", "s91");
  return (a01.x + a01.y) + (a23.x + a23.y);
}

// exact pow2 renorm: p *= 2^-e, cl += e*ln2
__device__ __forceinline__ void renorm(float& p, float& cl) {
  float mx = wred_max(p);
  int e = ((__builtin_bit_cast(int, mx) >> 23) & 255) - 127;
  float r = __builtin_bit_cast(float, (127 - e) << 23);
  p *= r;
  cl += (float)e * 0.6931471805599453f;
}

// ---------- fused kernel ----------
// blocks [0,1024): scan. even = forward half (alpha_1024), odd = backward half (beta_1024).
// blocks [1024,1536): gold-path score + mask count, one wave per batch.

extern "C" __global__ __launch_bounds__(64, 1)
void crf_main(const float* __restrict__ emis,
              const float* __restrict__ trans,
              const float* __restrict__ startt,
              const float* __restrict__ endt,
              const int*   __restrict__ tags,
              const float* __restrict__ mask,
              float* __restrict__ wa, float* __restrict__ wb,
              float* __restrict__ wsc, int* __restrict__ wcnt) {
  __shared__ float st[NTAGS * NTAGS];
  const int lane = threadIdx.x;
  const int bid  = blockIdx.x;

  if (bid >= 2 * NB) {
    // ----- score path -----
    const int b = bid - 2 * NB;
    for (int k = lane; k < NTAGS * NTAGS; k += 64) st[k] = trans[k];
    __syncthreads();
    const int* tb = tags + (size_t)b * SLEN;
    float ssum = 0.0f, csum = 0.0f;
    for (int it = 0; it < SLEN / 64; ++it) {
      const int t   = it * 64 + lane;
      int   cur = tb[t];
      float mv  = mask[(size_t)b * SLEN + t];
      float ev  = emis[((size_t)b * SLEN + t) * NTAGS + cur];
      float s;
      if (t == 0) {
        s = startt[cur] + ev;  // unmasked per reference
      } else {
        int prev = tb[t - 1];
        s = (mv != 0.0f) ? (st[prev * NTAGS + cur] + ev) : 0.0f;
      }
      ssum += s;
      csum += (mv != 0.0f) ? 1.0f : 0.0f;
    }
    ssum = wred_sum(ssum);
    csum = wred_sum(csum);
    if (lane == 0) { wsc[b] = ssum; wcnt[b] = (int)(csum + 0.5f); }
    return;
  }

  // ----- scan path -----
  const int  b   = bid >> 1;
  const bool fwd = (bid & 1) == 0;
  const int  jc  = lane < NTAGS ? lane : (NTAGS - 1);  // pad lanes mirror lane 47

  const float* eb = emis + (size_t)b * SLEN * NTAGS;
  const float* mb = mask + (size_t)b * SLEN;

  f32x2 Ev2[24];  // fwd: lane j holds column j of exp(trans); bwd: lane i holds row i
  if (fwd) {
#pragma unroll
    for (int i = 0; i < NTAGS; i += 2) {
      Ev2[i / 2].x = __expf(trans[(i + 0) * NTAGS + jc]);
      Ev2[i / 2].y = __expf(trans[(i + 1) * NTAGS + jc]);
    }
  } else {
#pragma unroll
    for (int j = 0; j < NTAGS; j += 2) {
      Ev2[j / 2].x = __expf(trans[jc * NTAGS + j + 0]);
      Ev2[j / 2].y = __expf(trans[jc * NTAGS + j + 1]);
    }
  }

  float ebuf[8];  // 8-deep emission prefetch ring, slot = t & 7
  float p, cl, een;

  if (fwd) {
    float mnext = mb[1 + (lane & 7)];  // masks for group 0 (bits 0..7 of ballot)
    float a0 = startt[jc] + eb[jc];
    if (lane >= NTAGS) a0 = -1e30f;
    float m0 = wred_max(a0);
    p  = __expf(a0 - m0);   // pad lanes: exp(-1e30-m0) = 0 -> stay harmless
    cl = m0;
#pragma unroll
    for (int k = 1; k <= 8; ++k) ebuf[k & 7] = eb[(size_t)k * NTAGS + jc];
    een = __expf(ebuf[1]);  // exp(emit_1)

    for (int g = 0; g < 128; ++g) {
      const int t0 = 1 + 8 * g;
      const uint32_t m8 = (uint32_t)__ballot(mnext != 0.0f) & 0xffu;
      mnext = mb[(size_t)(t0 + 8) + (lane & 7)];   // prefetch next group's masks
      if (m8 == 0xffu) {
        // fast path: all masked-in, no select on the chain
#pragma unroll
        for (int u = 0; u < 8; ++u) {
          const int t = t0 + u;
          float ee = een;                       // exp(emit_t), off-chain
          een = __expf(ebuf[(t + 1) & 7]);
          float acc = pipedot48(p, Ev2);
          p = acc * ee;
          ebuf[t & 7] = eb[(size_t)(t + 8) * NTAGS + jc];  // prefetch t+8
          if (u == 7) renorm(p, cl);
        }
      } else {
#pragma unroll
        for (int u = 0; u < 8; ++u) {
          const int t = t0 + u;
          float ee = een;
          een = __expf(ebuf[(t + 1) & 7]);
          float acc = pipedot48(p, Ev2);
          float pn  = acc * ee;
          p = ((m8 >> u) & 1u) ? pn : p;
          ebuf[t & 7] = eb[(size_t)(t + 8) * NTAGS + jc];
          if (u == 7) renorm(p, cl);
        }
      }
    }
    if (lane < NTAGS) wa[b * NTAGS + lane] = __logf(p) + cl;
  } else {
    float mnext = mb[2040 - (lane & 7)];  // masks for group 0 of main loop
    float b0 = endt[jc];
    if (lane >= NTAGS) b0 = -1e30f;
    float m0 = wred_max(b0);
    p  = __expf(b0 - m0);
    cl = m0;
#pragma unroll
    for (int k = 0; k < 8; ++k) ebuf[(2047 - k) & 7] = eb[(size_t)(2047 - k) * NTAGS + jc];
    float q = p * __expf(ebuf[7]);  // q_2047 = beta_2047 * exp(emit_2047)
    een = __expf(ebuf[6]);          // exp(emit_2046)

    // peel t = 2047..2041 to align groups of 8 (mask via per-step loads; off hot path)
#pragma unroll
    for (int pt = 0; pt < 7; ++pt) {
      const int t = 2047 - pt;
      float ee = een;                       // exp(emit_{t-1})
      een = __expf(ebuf[(t + 6) & 7]);      // emit_{t-2}
      float acc = pipedot48(q, Ev2);        // beta_{t-1}
      float mv  = mb[t];
      p = (mv != 0.0f) ? acc : p;
      ebuf[t & 7] = eb[(size_t)(t - 8) * NTAGS + jc];
      if (pt == 6) renorm(p, cl);
      q = p * ee;
    }
    for (int g = 0; g < 127; ++g) {
      const int t0 = 2040 - 8 * g;
      const uint32_t m8 = (uint32_t)__ballot(mnext != 0.0f) & 0xffu;  // bit u <-> t0-u
      mnext = mb[(size_t)(t0 - 8) - (lane & 7)];
      if (m8 == 0xffu) {
#pragma unroll
        for (int u = 0; u < 8; ++u) {
          const int t = t0 - u;               // down to 1025
          float ee = een;
          een = __expf(ebuf[(t + 6) & 7]);
          float acc = pipedot48(q, Ev2);
          p = acc;
          ebuf[t & 7] = eb[(size_t)(t - 8) * NTAGS + jc];
          if (u == 7) renorm(p, cl);
          q = p * ee;
        }
      } else {
#pragma unroll
        for (int u = 0; u < 8; ++u) {
          const int t = t0 - u;
          float ee = een;
          een = __expf(ebuf[(t + 6) & 7]);
          float acc = pipedot48(q, Ev2);
          p = ((m8 >> u) & 1u) ? acc : p;
          ebuf[t & 7] = eb[(size_t)(t - 8) * NTAGS + jc];
          if (u == 7) renorm(p, cl);
          q = p * ee;
        }
      }
    }
    if (lane < NTAGS) wb[b * NTAGS + lane] = __logf(p) + cl;
  }
}

// ---------- combine: one block, one thread per batch; no atomics ----------

extern "C" __global__ __launch_bounds__(512)
void crf_combine(const float* __restrict__ wa, const float* __restrict__ wb,
                 const float* __restrict__ wsc, const int* __restrict__ wcnt,
                 const int* __restrict__ tags, const float* __restrict__ endt,
                 float* __restrict__ out) {
  __shared__ float red[8];
  const int b = threadIdx.x;  // 512 threads = 512 batches
  float vv[NTAGS];
  float m = -1e30f;
#pragma unroll
  for (int j = 0; j < NTAGS; ++j) {
    vv[j] = wa[b * NTAGS + j] + wb[b * NTAGS + j];
    m = fmaxf(m, vv[j]);
  }
  float s = 0.0f;
#pragma unroll
  for (int j = 0; j < NTAGS; ++j) s += __expf(vv[j] - m);
  float part = m + __logf(s);
  const int   last  = wcnt[b] - 1;
  const float score = wsc[b] + endt[tags[(size_t)b * SLEN + last]];
  float val = (part - score) * (1.0f / (float)NB);
  float wsum = wred_sum(val);
  if ((b & 63) == 0) red[b >> 6] = wsum;
  __syncthreads();
  if (b == 0) {
    float t = 0.0f;
#pragma unroll
    for (int w = 0; w < 8; ++w) t += red[w];
    *out = t;
  }
}

// ---------- launch ----------

extern "C" void kernel_launch(void* const* d_in, const int* in_sizes, int n_in,
                              void* d_out, int out_size, void* d_ws, size_t ws_size,
                              hipStream_t stream) {
  const float* emis  = (const float*)d_in[0];
  const float* trans = (const float*)d_in[1];
  const float* stt   = (const float*)d_in[2];
  const float* ent   = (const float*)d_in[3];
  const int*   tags  = (const int*)d_in[4];
  const float* mask  = (const float*)d_in[5];

  float* wa   = (float*)d_ws;            // [NB][NTAGS]
  float* wb   = wa + NB * NTAGS;         // [NB][NTAGS]
  float* wsc  = wb + NB * NTAGS;         // [NB]
  int*   wcnt = (int*)(wsc + NB);        // [NB]

  crf_main<<<2 * NB + NB, 64, 0, stream>>>(emis, trans, stt, ent, tags, mask,
                                           wa, wb, wsc, wcnt);
  crf_combine<<<1, 512, 0, stream>>>(wa, wb, wsc, wcnt, tags, ent, (float*)d_out);
}

// Round 6
// 408.728 us; speedup vs baseline: 1.3674x; 1.0102x over previous
//
#include <hip/hip_runtime.h>

#define NTAGS 48
#define NB    512
#define SLEN  2048

typedef float f32x2 __attribute__((ext_vector_type(2)));

// ---------- cross-lane helpers (wave64, DPP) ----------

__device__ __forceinline__ float rl_f(float v, int l) {
  return __builtin_bit_cast(float, __builtin_amdgcn_readlane(__builtin_bit_cast(int, v), l));
}

template <int CTRL, bool BC>
__device__ __forceinline__ float dpp_mv(float oldv, float v) {
  return __builtin_bit_cast(float, __builtin_amdgcn_update_dpp(
      __builtin_bit_cast(int, oldv), __builtin_bit_cast(int, v), CTRL, 0xF, 0xF, BC));
}

__device__ __forceinline__ float wred_max(float v) {
  v = fmaxf(v, dpp_mv<0x128, false>(v, v));
  v = fmaxf(v, dpp_mv<0x124, false>(v, v));
  v = fmaxf(v, dpp_mv<0x122, false>(v, v));
  v = fmaxf(v, dpp_mv<0x121, false>(v, v));
  v = fmaxf(v, dpp_mv<0x142, false>(v, v));
  v = fmaxf(v, dpp_mv<0x143, false>(v, v));
  return rl_f(v, 63);
}

__device__ __forceinline__ float wred_sum(float v) {
  v += dpp_mv<0x128, true>(0.0f, v);
  v += dpp_mv<0x124, true>(0.0f, v);
  v += dpp_mv<0x122, true>(0.0f, v);
  v += dpp_mv<0x121, true>(0.0f, v);
  v += dpp_mv<0x142, true>(0.0f, v);
  v += dpp_mv<0x143, true>(0.0f, v);
  return rl_f(v, 63);
}

// broadcast-dot: y = sum_{i<48} p[i] * Ev[i].
// 48 v_readlane + 24 v_pk_fma, software-pipelined in ONE asm block with THREE
// rotating SGPR banks (A=s80-83, B=s84-87, C=s88-91): readlane group g+1
// issues between group g's readlanes and group g's FMAs, so every v_pk_fma
// reads SGPRs written >=5 instructions earlier (no SGPR-write->VALU-read
// hazard stalls). Pairing/accumulation order identical to r2 -> bitwise-
// identical result. (r5 measured: 222 -> 209 us.)
#define RL4(L0, L1, L2, L3, SA, SB, SC, SD)      \
  "v_readlane_b32 " SA ", %2, " #L0 "\n\t"       \
  "v_readlane_b32 " SB ", %2, " #L1 "\n\t"       \
  "v_readlane_b32 " SC ", %2, " #L2 "\n\t"       \
  "v_readlane_b32 " SD ", %2, " #L3 "\n\t"

#define FMA2(EA, EB, PA, PB)                     \
  "v_pk_fma_f32 %0, " PA ", " EA ", %0\n\t"      \
  "v_pk_fma_f32 %1, " PB ", " EB ", %1\n\t"

__device__ __forceinline__ float pipedot48(float pval, const f32x2* Ev2) {
  const int pv = __builtin_bit_cast(int, pval);
  f32x2 a01 = {0.0f, 0.0f};
  f32x2 a23 = {0.0f, 0.0f};
  asm(
    RL4(0, 1, 2, 3,     "s80", "s81", "s82", "s83")
    RL4(4, 5, 6, 7,     "s84", "s85", "s86", "s87")
    FMA2("%3",  "%4",   "s[80:81]", "s[82:83]")   // g0
    RL4(8, 9, 10, 11,   "s88", "s89", "s90", "s91")
    FMA2("%5",  "%6",   "s[84:85]", "s[86:87]")   // g1
    RL4(12, 13, 14, 15, "s80", "s81", "s82", "s83")
    FMA2("%7",  "%8",   "s[88:89]", "s[90:91]")   // g2
    RL4(16, 17, 18, 19, "s84", "s85", "s86", "s87")
    FMA2("%9",  "%10",  "s[80:81]", "s[82:83]")   // g3
    RL4(20, 21, 22, 23, "s88", "s89", "s90", "s91")
    FMA2("%11", "%12",  "s[84:85]", "s[86:87]")   // g4
    RL4(24, 25, 26, 27, "s80", "s81", "s82", "s83")
    FMA2("%13", "%14",  "s[88:89]", "s[90:91]")   // g5
    RL4(28, 29, 30, 31, "s84", "s85", "s86", "s87")
    FMA2("%15", "%16",  "s[80:81]", "s[82:83]")   // g6
    RL4(32, 33, 34, 35, "s88", "s89", "s90", "s91")
    FMA2("%17", "%18",  "s[84:85]", "s[86:87]")   // g7
    RL4(36, 37, 38, 39, "s80", "s81", "s82", "s83")
    FMA2("%19", "%20",  "s[88:89]", "s[90:91]")   // g8
    RL4(40, 41, 42, 43, "s84", "s85", "s86", "s87")
    FMA2("%21", "%22",  "s[80:81]", "s[82:83]")   // g9
    RL4(44, 45, 46, 47, "s88", "s89", "s90", "s91")
    FMA2("%23", "%24",  "s[84:85]", "s[86:87]")   // g10
    FMA2("%25", "%26",  "s[88:89]", "s[90:91]")   // g11
    : "+v"(a01), "+v"(a23)
    : "v"(pv),
      "v"(Ev2[0]),  "v"(Ev2[1]),  "v"(Ev2[2]),  "v"(Ev2[3]),
      "v"(Ev2[4]),  "v"(Ev2[5]),  "v"(Ev2[6]),  "v"(Ev2[7]),
      "v"(Ev2[8]),  "v"(Ev2[9]),  "v"(Ev2[10]), "v"(Ev2[11]),
      "v"(Ev2[12]), "v"(Ev2[13]), "v"(Ev2[14]), "v"(Ev2[15]),
      "v"(Ev2[16]), "v"(Ev2[17]), "v"(Ev2[18]), "v"(Ev2[19]),
      "v"(Ev2[20]), "v"(Ev2[21]), "v"(Ev2[22]), "v"(Ev2[23])
    : "s80", "s81", "s82", "s83", "s84", "s85",
      "s86", "s87", "s88", "s89", "s90", "s91");
  return (a01.x + a01.y) + (a23.x + a23.y);
}

// exact pow2 renorm: p *= 2^-e, cl += e*ln2
__device__ __forceinline__ void renorm(float& p, float& cl) {
  float mx = wred_max(p);
  int e = ((__builtin_bit_cast(int, mx) >> 23) & 255) - 127;
  float r = __builtin_bit_cast(float, (127 - e) << 23);
  p *= r;
  cl += (float)e * 0.6931471805599453f;
}

// ---------- fused kernel ----------
// blocks [0,1024): scan. even = forward half (alpha_1024), odd = backward half (beta_1024).
// blocks [1024,1536): gold-path score + mask count, one wave per batch.

extern "C" __global__ __launch_bounds__(64, 1)
void crf_main(const float* __restrict__ emis,
              const float* __restrict__ trans,
              const float* __restrict__ startt,
              const float* __restrict__ endt,
              const int*   __restrict__ tags,
              const float* __restrict__ mask,
              float* __restrict__ wa, float* __restrict__ wb,
              float* __restrict__ wsc, int* __restrict__ wcnt) {
  __shared__ float st[NTAGS * NTAGS];
  const int lane = threadIdx.x;
  const int bid  = blockIdx.x;

  if (bid >= 2 * NB) {
    // ----- score path -----
    const int b = bid - 2 * NB;
    for (int k = lane; k < NTAGS * NTAGS; k += 64) st[k] = trans[k];
    __syncthreads();
    const int* tb = tags + (size_t)b * SLEN;
    float ssum = 0.0f, csum = 0.0f;
    for (int it = 0; it < SLEN / 64; ++it) {
      const int t   = it * 64 + lane;
      int   cur = tb[t];
      float mv  = mask[(size_t)b * SLEN + t];
      float ev  = emis[((size_t)b * SLEN + t) * NTAGS + cur];
      float s;
      if (t == 0) {
        s = startt[cur] + ev;  // unmasked per reference
      } else {
        int prev = tb[t - 1];
        s = (mv != 0.0f) ? (st[prev * NTAGS + cur] + ev) : 0.0f;
      }
      ssum += s;
      csum += (mv != 0.0f) ? 1.0f : 0.0f;
    }
    ssum = wred_sum(ssum);
    csum = wred_sum(csum);
    if (lane == 0) { wsc[b] = ssum; wcnt[b] = (int)(csum + 0.5f); }
    return;
  }

  // ----- scan path -----
  const int  b   = bid >> 1;
  const bool fwd = (bid & 1) == 0;
  const int  jc  = lane < NTAGS ? lane : (NTAGS - 1);  // pad lanes mirror lane 47

  const float* eb = emis + (size_t)b * SLEN * NTAGS;
  const float* mb = mask + (size_t)b * SLEN;

  f32x2 Ev2[24];  // fwd: lane j holds column j of exp(trans); bwd: lane i holds row i
  if (fwd) {
#pragma unroll
    for (int i = 0; i < NTAGS; i += 2) {
      Ev2[i / 2].x = __expf(trans[(i + 0) * NTAGS + jc]);
      Ev2[i / 2].y = __expf(trans[(i + 1) * NTAGS + jc]);
    }
  } else {
#pragma unroll
    for (int j = 0; j < NTAGS; j += 2) {
      Ev2[j / 2].x = __expf(trans[jc * NTAGS + j + 0]);
      Ev2[j / 2].y = __expf(trans[jc * NTAGS + j + 1]);
    }
  }

  float ebuf[8];  // 8-deep emission prefetch ring, slot = t & 7
  float p, cl, een;

  if (fwd) {
    float mnext = mb[1 + (lane & 7)];  // masks for group 0 (bits 0..7 of ballot)
    float a0 = startt[jc] + eb[jc];
    if (lane >= NTAGS) a0 = -1e30f;
    float m0 = wred_max(a0);
    p  = __expf(a0 - m0);   // pad lanes: exp(-1e30-m0) = 0 -> stay harmless
    cl = m0;
#pragma unroll
    for (int k = 1; k <= 8; ++k) ebuf[k & 7] = eb[(size_t)k * NTAGS + jc];
    een = __expf(ebuf[1]);  // exp(emit_1)

    for (int g = 0; g < 128; ++g) {
      const int t0 = 1 + 8 * g;
      const uint32_t m8 = (uint32_t)__ballot(mnext != 0.0f) & 0xffu;
      mnext = mb[(size_t)(t0 + 8) + (lane & 7)];   // prefetch next group's masks
      if (m8 == 0xffu) {
        // fast path: all masked-in, no select on the chain
#pragma unroll
        for (int u = 0; u < 8; ++u) {
          const int t = t0 + u;
          float ee = een;                       // exp(emit_t), off-chain
          een = __expf(ebuf[(t + 1) & 7]);
          float acc = pipedot48(p, Ev2);
          p = acc * ee;
          ebuf[t & 7] = eb[(size_t)(t + 8) * NTAGS + jc];  // prefetch t+8
          if (u == 7) renorm(p, cl);
        }
      } else {
#pragma unroll
        for (int u = 0; u < 8; ++u) {
          const int t = t0 + u;
          float ee = een;
          een = __expf(ebuf[(t + 1) & 7]);
          float acc = pipedot48(p, Ev2);
          float pn  = acc * ee;
          p = ((m8 >> u) & 1u) ? pn : p;
          ebuf[t & 7] = eb[(size_t)(t + 8) * NTAGS + jc];
          if (u == 7) renorm(p, cl);
        }
      }
    }
    if (lane < NTAGS) wa[b * NTAGS + lane] = __logf(p) + cl;
  } else {
    float mnext = mb[2040 - (lane & 7)];  // masks for group 0 of main loop
    float b0 = endt[jc];
    if (lane >= NTAGS) b0 = -1e30f;
    float m0 = wred_max(b0);
    p  = __expf(b0 - m0);
    cl = m0;
#pragma unroll
    for (int k = 0; k < 8; ++k) ebuf[(2047 - k) & 7] = eb[(size_t)(2047 - k) * NTAGS + jc];
    float q = p * __expf(ebuf[7]);  // q_2047 = beta_2047 * exp(emit_2047)
    een = __expf(ebuf[6]);          // exp(emit_2046)

    // peel t = 2047..2041 to align groups of 8 (mask via per-step loads; off hot path)
#pragma unroll
    for (int pt = 0; pt < 7; ++pt) {
      const int t = 2047 - pt;
      float ee = een;                       // exp(emit_{t-1})
      een = __expf(ebuf[(t + 6) & 7]);      // emit_{t-2}
      float acc = pipedot48(q, Ev2);        // beta_{t-1}
      float mv  = mb[t];
      p = (mv != 0.0f) ? acc : p;
      ebuf[t & 7] = eb[(size_t)(t - 8) * NTAGS + jc];
      if (pt == 6) renorm(p, cl);
      q = p * ee;
    }
    for (int g = 0; g < 127; ++g) {
      const int t0 = 2040 - 8 * g;
      const uint32_t m8 = (uint32_t)__ballot(mnext != 0.0f) & 0xffu;  // bit u <-> t0-u
      mnext = mb[(size_t)(t0 - 8) - (lane & 7)];
      if (m8 == 0xffu) {
#pragma unroll
        for (int u = 0; u < 8; ++u) {
          const int t = t0 - u;               // down to 1025
          float ee = een;
          een = __expf(ebuf[(t + 6) & 7]);
          float acc = pipedot48(q, Ev2);
          p = acc;
          ebuf[t & 7] = eb[(size_t)(t - 8) * NTAGS + jc];
          if (u == 7) renorm(p, cl);
          q = p * ee;
        }
      } else {
#pragma unroll
        for (int u = 0; u < 8; ++u) {
          const int t = t0 - u;
          float ee = een;
          een = __expf(ebuf[(t + 6) & 7]);
          float acc = pipedot48(q, Ev2);
          p = ((m8 >> u) & 1u) ? acc : p;
          ebuf[t & 7] = eb[(size_t)(t - 8) * NTAGS + jc];
          if (u == 7) renorm(p, cl);
          q = p * ee;
        }
      }
    }
    if (lane < NTAGS) wb[b * NTAGS + lane] = __logf(p) + cl;
  }
}

// ---------- combine stage 1: 512 blocks, one wave per batch ----------
// Coalesced: lane j reads wa/wb[b*48+j] (contiguous 192 B per block).
// Replaces the 1-block combine whose per-thread j-loop made every load a
// 64-cacheline stride-192B gather on a single CU (suspected ~200 us tail),
// and the older 512-way same-address atomicAdd (serialized cross-XCD).
// No atomics: partial per batch -> wpart[b]; stage 2 reduces.

extern "C" __global__ __launch_bounds__(64)
void crf_combine1(const float* __restrict__ wa, const float* __restrict__ wb,
                  const float* __restrict__ wsc, const int* __restrict__ wcnt,
                  const int* __restrict__ tags, const float* __restrict__ endt,
                  float* __restrict__ wpart) {
  const int b    = blockIdx.x;
  const int lane = threadIdx.x;
  float v = -1e30f;
  if (lane < NTAGS) v = wa[b * NTAGS + lane] + wb[b * NTAGS + lane];
  float m = wred_max(v);
  float s = wred_sum(__expf(v - m));
  float part = m + __logf(s);
  if (lane == 0) {
    const int   last  = wcnt[b] - 1;
    const float score = wsc[b] + endt[tags[(size_t)b * SLEN + last]];
    wpart[b] = (part - score) * (1.0f / (float)NB);
  }
}

// ---------- combine stage 2: one wave sums 512 partials ----------

extern "C" __global__ __launch_bounds__(64)
void crf_combine2(const float* __restrict__ wpart, float* __restrict__ out) {
  const int lane = threadIdx.x;
  float s = 0.0f;
#pragma unroll
  for (int k = 0; k < NB / 64; ++k) s += wpart[k * 64 + lane];  // coalesced
  float t = wred_sum(s);
  if (lane == 0) *out = t;
}

// ---------- launch ----------

extern "C" void kernel_launch(void* const* d_in, const int* in_sizes, int n_in,
                              void* d_out, int out_size, void* d_ws, size_t ws_size,
                              hipStream_t stream) {
  const float* emis  = (const float*)d_in[0];
  const float* trans = (const float*)d_in[1];
  const float* stt   = (const float*)d_in[2];
  const float* ent   = (const float*)d_in[3];
  const int*   tags  = (const int*)d_in[4];
  const float* mask  = (const float*)d_in[5];

  float* wa    = (float*)d_ws;            // [NB][NTAGS]
  float* wb    = wa + NB * NTAGS;         // [NB][NTAGS]
  float* wsc   = wb + NB * NTAGS;         // [NB]
  int*   wcnt  = (int*)(wsc + NB);        // [NB]
  float* wpart = (float*)(wcnt + NB);     // [NB]

  crf_main<<<2 * NB + NB, 64, 0, stream>>>(emis, trans, stt, ent, tags, mask,
                                           wa, wb, wsc, wcnt);
  crf_combine1<<<NB, 64, 0, stream>>>(wa, wb, wsc, wcnt, tags, ent, wpart);
  crf_combine2<<<1, 64, 0, stream>>>(wpart, (float*)d_out);
}